// Round 1
// baseline (124.184 us; speedup 1.0000x reference)
//
#include <hip/hip_runtime.h>
#include <hip/hip_bf16.h>

typedef __attribute__((ext_vector_type(8))) short short8;
typedef __attribute__((ext_vector_type(4))) float f32x4;

#define BM 128
#define BN 128
#define BK 64
#define THREADS 512
#define IN_F 512
#define OUT_F 512
#define PHI_STEPS 64
#define NSTEPS 72

__device__ __forceinline__ short f2bf(float f) {
  __hip_bfloat16 h = __float2bfloat16(f);
  return __builtin_bit_cast(short, h);
}

__global__ void __launch_bounds__(THREADS) kan_fused(
    const float* __restrict__ x, const float* __restrict__ rw,
    const float* __restrict__ rc, const float* __restrict__ w,
    const float* __restrict__ bias, const float* __restrict__ sb,
    float* __restrict__ out) {
  // A tile: [BM][BK] bf16, row = m (128 B/row), 8 slots of 16 B, XOR-swizzled by (m&7)
  // B tile: [BN][BK] bf16 (n-major = B^T), same swizzle by (n&7)
  __shared__ __align__(16) short A_lds[BM * BK];
  __shared__ __align__(16) short B_lds[BN * BK];

  const int t = threadIdx.x;
  const int lane = t & 63;
  const int wid = t >> 6;       // 0..7
  const int wm = wid >> 2;      // 0..1 (64 rows each)
  const int wn = wid & 3;       // 0..3 (32 cols each)
  const int l15 = lane & 15;
  const int kb = lane >> 4;     // 0..3

  const int m0 = blockIdx.x * BM;
  const int n0 = blockIdx.y * BN;

  f32x4 acc[4][2];
#pragma unroll
  for (int i = 0; i < 4; ++i)
#pragma unroll
    for (int j = 0; j < 2; ++j) acc[i][j] = (f32x4){0.f, 0.f, 0.f, 0.f};

  // A staging: 1024 (m, i_loc) tasks over 512 threads x 2 iters
  const int a_iloc = t & 7;     // which feature octet / which feature within step
  const int a_mb = t >> 3;      // 0..63 (iter adds 64)
  // B staging: 1024 (n, oct) tasks
  const int b_n = t & 127;
  const int b_oct0 = t >> 7;    // 0..3 (iter adds 4)

  const float nbeta = -64.0f / 9.0f;  // -(nb/log2(nb))^2

  for (int s = 0; s < NSTEPS; ++s) {
    __syncthreads();  // previous MFMA reads done before overwrite

    // ---------------- stage A ----------------
    if (s < PHI_STEPS) {
      // K layout: k_local = i_loc*8 + b ; feature i = s*8 + i_loc
      const int feat = s * 8 + a_iloc;
      const float4 rw0 = *(const float4*)(rw + feat * 8);
      const float4 rw1 = *(const float4*)(rw + feat * 8 + 4);
      const float4 rc0 = *(const float4*)(rc + feat * 8);
      const float4 rc1 = *(const float4*)(rc + feat * 8 + 4);
      const float rwv[8] = {rw0.x, rw0.y, rw0.z, rw0.w, rw1.x, rw1.y, rw1.z, rw1.w};
      const float rcv[8] = {rc0.x, rc0.y, rc0.z, rc0.w, rc1.x, rc1.y, rc1.z, rc1.w};
#pragma unroll
      for (int iter = 0; iter < 2; ++iter) {
        const int m = a_mb + iter * 64;
        const float xv = x[(m0 + m) * IN_F + feat];
        short8 av;
#pragma unroll
        for (int b = 0; b < 8; ++b) {
          const float z = fmaf(xv, rwv[b], -rcv[b]);
          av[b] = f2bf(__expf(nbeta * z * z));
        }
        const int slot = a_iloc ^ (m & 7);
        *(short8*)&A_lds[m * BK + slot * 8] = av;
      }
    } else {
      // cos(x) tail: k_local = a_iloc*8 + j -> feature = (s-64)*64 + k_local
      const int f0 = (s - PHI_STEPS) * 64 + a_iloc * 8;
#pragma unroll
      for (int iter = 0; iter < 2; ++iter) {
        const int m = a_mb + iter * 64;
        const float4 xa = *(const float4*)(x + (m0 + m) * IN_F + f0);
        const float4 xb = *(const float4*)(x + (m0 + m) * IN_F + f0 + 4);
        short8 av;
        av[0] = f2bf(__cosf(xa.x)); av[1] = f2bf(__cosf(xa.y));
        av[2] = f2bf(__cosf(xa.z)); av[3] = f2bf(__cosf(xa.w));
        av[4] = f2bf(__cosf(xb.x)); av[5] = f2bf(__cosf(xb.y));
        av[6] = f2bf(__cosf(xb.z)); av[7] = f2bf(__cosf(xb.w));
        const int slot = a_iloc ^ (m & 7);
        *(short8*)&A_lds[m * BK + slot * 8] = av;
      }
    }

    // ---------------- stage B (transpose f32 -> bf16 n-major) ----------------
    {
      const float* Bsrc = (s < PHI_STEPS) ? (w + s * 64 * OUT_F)
                                          : (sb + (s - PHI_STEPS) * 64 * OUT_F);
#pragma unroll
      for (int iter = 0; iter < 2; ++iter) {
        const int oct = b_oct0 + iter * 4;
        const float* src = Bsrc + (oct * 8) * OUT_F + n0 + b_n;
        short8 bv;
#pragma unroll
        for (int j = 0; j < 8; ++j) bv[j] = f2bf(src[j * OUT_F]);
        const int slot = oct ^ (b_n & 7);
        *(short8*)&B_lds[b_n * BK + slot * 8] = bv;
      }
    }

    __syncthreads();

    // ---------------- MFMA ----------------
#pragma unroll
    for (int kk = 0; kk < 2; ++kk) {
      short8 af[4], bfr[2];
#pragma unroll
      for (int mi = 0; mi < 4; ++mi) {
        const int row = wm * 64 + mi * 16 + l15;
        const int slot = (kk * 4 + kb) ^ (row & 7);
        af[mi] = *(const short8*)&A_lds[row * BK + slot * 8];
      }
#pragma unroll
      for (int ni = 0; ni < 2; ++ni) {
        const int row = wn * 32 + ni * 16 + l15;
        const int slot = (kk * 4 + kb) ^ (row & 7);
        bfr[ni] = *(const short8*)&B_lds[row * BK + slot * 8];
      }
#pragma unroll
      for (int mi = 0; mi < 4; ++mi)
#pragma unroll
        for (int ni = 0; ni < 2; ++ni)
          acc[mi][ni] = __builtin_amdgcn_mfma_f32_16x16x32_bf16(
              af[mi], bfr[ni], acc[mi][ni], 0, 0, 0);
    }
  }

  // ---------------- epilogue: bias + store ----------------
#pragma unroll
  for (int ni = 0; ni < 2; ++ni) {
    const int col = n0 + wn * 32 + ni * 16 + l15;
    const float bv = bias[col];
#pragma unroll
    for (int mi = 0; mi < 4; ++mi) {
      const int rowb = m0 + wm * 64 + mi * 16 + kb * 4;
#pragma unroll
      for (int r = 0; r < 4; ++r)
        out[(rowb + r) * OUT_F + col] = acc[mi][ni][r] + bv;
    }
  }
}

extern "C" void kernel_launch(void* const* d_in, const int* in_sizes, int n_in,
                              void* d_out, int out_size, void* d_ws, size_t ws_size,
                              hipStream_t stream) {
  const float* x    = (const float*)d_in[0];
  const float* rw   = (const float*)d_in[1];
  const float* rc   = (const float*)d_in[2];
  const float* w    = (const float*)d_in[3];
  const float* bias = (const float*)d_in[4];
  const float* sb   = (const float*)d_in[5];
  float* out = (float*)d_out;

  const int nrows = in_sizes[0] / IN_F;  // 8192
  dim3 grid(nrows / BM, OUT_F / BN);     // (64, 4)
  kan_fused<<<grid, THREADS, 0, stream>>>(x, rw, rc, w, bias, sb, out);
}